// Round 13
// baseline (415.295 us; speedup 1.0000x reference)
//
#include <hip/hip_runtime.h>
#include <hip/hip_bf16.h>
#include <stdint.h>

// ---------- types ----------
typedef __attribute__((ext_vector_type(8)))  short bf16x8;   // MFMA A/B frag (4 VGPR)
typedef __attribute__((ext_vector_type(16))) float f32x16;   // 32x32 MFMA C/D frag

__device__ __forceinline__ unsigned short f2bf(float f) {
  unsigned int u = __float_as_uint(f);
  u += 0x7FFFu + ((u >> 16) & 1u);   // round-to-nearest-even
  return (unsigned short)(u >> 16);
}

__device__ __forceinline__ void async_cp16(const void* g, void* l) {
  __builtin_amdgcn_global_load_lds((const __attribute__((address_space(1))) void*)g,
                                   (__attribute__((address_space(3))) void*)l,
                                   16, 0, 0);
}

// ---------- merged fp32 -> bf16 conversion (one launch for x, wug-perm, wd) --
// float4-unit ranges: x [0, 7340032), wug [7340032, 14680064), wd [.., 18350080)
// wug permute (64-row groups): out row r: g = r>>6, w = r&63;
//   src = g*32 + (w&31) + (w>=32 ? 2048 : 0)
// -> each 64-row group = 32 gate rows + 32 up rows of the same 32-wide e-block,
// so the two 32-col n-frags of a wave pair gate/up IN-LANE (col = lane&31).
__global__ __launch_bounds__(256) void cvt_all(const float* __restrict__ x,
                                               const float* __restrict__ wug,
                                               const float* __restrict__ wd,
                                               unsigned short* __restrict__ xb,
                                               unsigned short* __restrict__ wub,
                                               unsigned short* __restrict__ wdb) {
  int i = blockIdx.x * blockDim.x + threadIdx.x;
  const int stride = gridDim.x * blockDim.x;
  for (; i < 18350080; i += stride) {
    float4 v; ushort4* dp;
    if (i < 7340032) {
      v = ((const float4*)x)[i];
      dp = (ushort4*)xb + i;
    } else if (i < 14680064) {
      const int k = i - 7340032;
      const int r = k / 1792, c = k - r * 1792;
      const int g = r >> 6, w = r & 63;
      const int src = g * 32 + (w & 31) + ((w & 32) ? 2048 : 0);
      v = ((const float4*)wug)[(size_t)src * 1792 + c];
      dp = (ushort4*)wub + k;
    } else {
      const int k = i - 14680064;
      v = ((const float4*)wd)[k];
      dp = (ushort4*)wdb + k;
    }
    ushort4 o;
    o.x = f2bf(v.x); o.y = f2bf(v.y); o.z = f2bf(v.z); o.w = f2bf(v.w);
    *dp = o;
  }
}

// ---------- 256x256 NT bf16 GEMM: round-9 skeleton + mfma_32x32x16 ----------
// Round-12 + FIXED swizzle. Round-12's 2.2e7 bank conflicts: LDS serves lanes
// in STRIDE-8 groups {k,k+8,...,k+56} (only model consistent with rounds
// 9/12/6 counter data). Row-per-line layout with f(r)=r&7 repeats the slot for
// rows r,r+8,r+16,r+24 -> 4-8-way conflict. Fix: f(r) = (r&7) ^ (((r>>3)&3)<<1)
// -> stride-group rows get XOR {0,2,4,6} -> 8 distinct slots/group, both hi.
//   staging: (row>>3)&3 = wave&3  -> qgl = p7 ^ l3 ^ ((wave&3)<<1)
//   reading: (row>>3)&3 = (l31>>3)&3 (mt*32,wr*128,wc*64 all ==0 mod 32)
//            -> slot = (kst*2+hi) ^ (l31&7) ^ ((l31>>3)<<1), uniform A/B.
// Involution: element (row r, global chunk q) at physical p = q ^ f(r);
// reader fetches physical (kst*2+hi) ^ f(r). Everything else = round-12:
// C[m,n] = sum_k A[m,k]*B[n,k]. 512 thr = 8 waves (2Mx4N), wave-tile 128x64.
// MFMA 32x32x16 (2382 TF ceiling vs 2075; 4x fewer instructions). acc 4x2
// f32x16. LDS 2 x (A 32K | B 32K) = 128 KiB, BK=64. Per K-tile: top half
// {read A mt0-1 + B all; stage G_first(t+1)=6; 16 MFMA; vmcnt(6); bar},
// bottom half {read A mt2-3; stage G_late(t+1)=2; 16 MFMA; vmcnt(2); bar}.
// Counted vmcnt only (never 0 except final). No inline lgkm asm.
// C/D layout (m74/m101): col = lane&31, row = (reg&3)+8*(reg>>2)+4*(l>>5).
// FUSE_SWIGLU: B pre-permuted (64-row groups) -> nt0 = gate, nt1 = up of the
// same e-cols in-lane; h = silu(g)*u, write [M, N/2] bf16.
template <int K, int N, bool FUSE_SWIGLU>
__global__ __launch_bounds__(512, 1) void gemm_nt(const unsigned short* __restrict__ A,
                                                  const unsigned short* __restrict__ B,
                                                  void* __restrict__ Cv) {
  extern __shared__ char sm[];   // 131072 B: buf{0,1} x [A 32K | B 32K]
  constexpr int nbx = N / 256;
  constexpr int nwg = (4096 / 256) * nbx;
  constexpr size_t K2 = (size_t)K * 2;
  constexpr int nt = K / 64;     // K-tiles

  // T1: bijective XCD swizzle (nwg % 8 == 0 for both GEMMs)
  const int bid = blockIdx.x;
  constexpr int q8 = nwg / 8;
  const int swz = (bid & 7) * q8 + (bid >> 3);
  const int bx = swz % nbx, by = swz / nbx;
  const int row0 = by * 256, col0 = bx * 256;

  const int tid = threadIdx.x, wave = tid >> 6, lane = tid & 63;
  const int wr = wave >> 2, wc = wave & 3;       // wave 2x4 grid
  const int l31 = lane & 31, hi = lane >> 5;

  // ---- staging setup: per thread 1 load per 8KB quarter (64 rows x 128B) ----
  const int l3 = lane >> 3, p7 = lane & 7;
  const int qgl = p7 ^ l3 ^ ((wave & 3) << 1);   // pre-swizzled logical 16B slot
  const char* srcA = (const char*)A + (size_t)(row0 + wave * 8 + l3) * K2 + qgl * 16;
  const char* srcB = (const char*)B + (size_t)(col0 + wave * 8 + l3) * K2 + qgl * 16;
  const int dstq = wave * 1024 + lane * 16; // linear dest within a quarter

#define STAGE_AQ(qa, tt, bufo) \
  async_cp16(srcA + (size_t)(qa) * 64 * K2 + (size_t)(tt) * 128, \
             sm + (bufo) + (qa) * 8192 + dstq)
#define STAGE_BQ(qb, tt, bufo) \
  async_cp16(srcB + (size_t)(qb) * 64 * K2 + (size_t)(tt) * 128, \
             sm + (bufo) + 32768 + (qb) * 8192 + dstq)

  // ---- fragment read offsets: row r byte = r*128 + (((kst*2+hi) ^ f(r))*16,
  //      f(r) = (r&7) ^ (((r>>3)&3)<<1); for reads (r>>3)&3 = (l31>>3)&3 ----
  const int fRow = (l31 & 7) ^ ((l31 >> 3) << 1);
  int sK[4];                                 // per-kst swizzled slot bytes
#pragma unroll
  for (int kst = 0; kst < 4; ++kst)
    sK[kst] = ((((kst << 1) | hi) ^ fRow) & 7) << 4;
  const int offAb = wr * 128 * 128 + l31 * 128;          // + mt*4096 + sK[kst]
  const int offBb = 32768 + wc * 64 * 128 + l31 * 128;   // + nt*4096 + sK[kst]

  f32x16 acc[4][2];
#pragma unroll
  for (int m = 0; m < 4; ++m)
#pragma unroll
    for (int n = 0; n < 2; ++n)
#pragma unroll
      for (int j = 0; j < 16; ++j) acc[m][n][j] = 0.f;

  // prologue: stage tile 0 (G_first 6, then G_late 2); drain G_first; sync
  STAGE_AQ(0, 0, 0); STAGE_AQ(2, 0, 0);
  STAGE_BQ(0, 0, 0); STAGE_BQ(1, 0, 0); STAGE_BQ(2, 0, 0); STAGE_BQ(3, 0, 0);
  STAGE_AQ(1, 0, 0); STAGE_AQ(3, 0, 0);
  asm volatile("s_waitcnt vmcnt(2)" ::: "memory");
  __builtin_amdgcn_s_barrier();

  // invariant at tile-t top: G_first(t) resident; own outstanding = G_late(t)=2
  for (int t = 0; t < nt; ++t) {
    const char* cur = sm + (t & 1) * 65536;
    const int nxo = ((t + 1) & 1) * 65536;
    const bool more = (t + 1 < nt);

    // ======== top half: mt0-1 x nt0-1, all 4 ksts ========
    bf16x8 a0[2][4], b[2][4];
#pragma unroll
    for (int mt = 0; mt < 2; ++mt)
#pragma unroll
      for (int kst = 0; kst < 4; ++kst)
        a0[mt][kst] = *(const bf16x8*)(cur + offAb + mt * 4096 + sK[kst]);
#pragma unroll
    for (int n = 0; n < 2; ++n)
#pragma unroll
      for (int kst = 0; kst < 4; ++kst)
        b[n][kst] = *(const bf16x8*)(cur + offBb + n * 4096 + sK[kst]);
    if (more) {   // stage G_first(t+1): A quads 0,2 + all B (6 loads)
      STAGE_AQ(0, t + 1, nxo); STAGE_AQ(2, t + 1, nxo);
      STAGE_BQ(0, t + 1, nxo); STAGE_BQ(1, t + 1, nxo);
      STAGE_BQ(2, t + 1, nxo); STAGE_BQ(3, t + 1, nxo);
    }
    __builtin_amdgcn_s_setprio(1);
#pragma unroll
    for (int kst = 0; kst < 4; ++kst)
#pragma unroll
      for (int mt = 0; mt < 2; ++mt)
#pragma unroll
        for (int n = 0; n < 2; ++n)
          acc[mt][n] = __builtin_amdgcn_mfma_f32_32x32x16_bf16(a0[mt][kst], b[n][kst], acc[mt][n], 0, 0, 0);
    __builtin_amdgcn_s_setprio(0);
    if (more) { asm volatile("s_waitcnt vmcnt(6)" ::: "memory"); }  // G_late(t) resident
    else      { asm volatile("s_waitcnt vmcnt(0)" ::: "memory"); }
    __builtin_amdgcn_s_barrier();

    // ======== bottom half: mt2-3 x nt0-1 (B frags live in regs) ========
    bf16x8 a1[2][4];
#pragma unroll
    for (int mt = 0; mt < 2; ++mt)
#pragma unroll
      for (int kst = 0; kst < 4; ++kst)
        a1[mt][kst] = *(const bf16x8*)(cur + offAb + (mt + 2) * 4096 + sK[kst]);
    if (more) { STAGE_AQ(1, t + 1, nxo); STAGE_AQ(3, t + 1, nxo); }  // G_late(t+1)
    __builtin_amdgcn_s_setprio(1);
#pragma unroll
    for (int kst = 0; kst < 4; ++kst)
#pragma unroll
      for (int mt = 0; mt < 2; ++mt)
#pragma unroll
        for (int n = 0; n < 2; ++n)
          acc[mt + 2][n] = __builtin_amdgcn_mfma_f32_32x32x16_bf16(a1[mt][kst], b[n][kst], acc[mt + 2][n], 0, 0, 0);
    __builtin_amdgcn_s_setprio(0);
    if (more) {
      asm volatile("s_waitcnt vmcnt(2)" ::: "memory");  // G_first(t+1) resident
      __builtin_amdgcn_s_barrier();
    }
  }
#undef STAGE_AQ
#undef STAGE_BQ

  // ---- epilogue: C/D col = lane&31, row = (j&3) + 8*(j>>2) + 4*hi ----
  const int rowb = row0 + wr * 128;
  if (FUSE_SWIGLU) {
    // nt0 = gate, nt1 = up, same e-cols in-lane (64-row pre-permuted B)
    unsigned short* Hp = (unsigned short*)Cv;
    const int ecb = ((col0 + wc * 64) >> 1) + l31;
#pragma unroll
    for (int mt = 0; mt < 4; ++mt)
#pragma unroll
      for (int j = 0; j < 16; ++j) {
        const int row = rowb + mt * 32 + (j & 3) + 8 * (j >> 2) + 4 * hi;
        const float gv = acc[mt][0][j];
        const float uv = acc[mt][1][j];
        const float s  = gv / (1.0f + __expf(-gv));
        Hp[(size_t)row * (N / 2) + ecb] = f2bf(s * uv);
      }
  } else {
    float* Cp = (float*)Cv;
    const int colb = col0 + wc * 64 + l31;
#pragma unroll
    for (int mt = 0; mt < 4; ++mt)
#pragma unroll
      for (int n = 0; n < 2; ++n)
#pragma unroll
        for (int j = 0; j < 16; ++j) {
          const int row = rowb + mt * 32 + (j & 3) + 8 * (j >> 2) + 4 * hi;
          Cp[(size_t)row * N + (colb + n * 32)] = acc[mt][n][j];
        }
  }
}

// ---------- launch ----------
extern "C" void kernel_launch(void* const* d_in, const int* in_sizes, int n_in,
                              void* d_out, int out_size, void* d_ws, size_t ws_size,
                              hipStream_t stream) {
  const int M = 4096, K = 7168, E = 2048;

  const float* x   = (const float*)d_in[0];  // [M,K]
  const float* wug = (const float*)d_in[1];  // [2E,K]
  const float* wd  = (const float*)d_in[2];  // [K,E]
  float* out = (float*)d_out;                // [M,K]

  // workspace layout (bytes)
  char* ws = (char*)d_ws;
  unsigned short* xb  = (unsigned short*)(ws);               //  58,720,256
  unsigned short* wub = (unsigned short*)(ws + 58720256);    //  58,720,256 (permuted)
  unsigned short* wdb = (unsigned short*)(ws + 117440512);   //  29,360,128
  unsigned short* h   = (unsigned short*)(ws + 146800640);   //  16,777,216
  if (ws_size < 163577856) return;                           // need ~156 MiB

  // allow 128 KiB dynamic LDS (host-side calls, safe under graph capture)
  hipFuncSetAttribute((const void*)gemm_nt<7168, 4096, true>,
                      hipFuncAttributeMaxDynamicSharedMemorySize, 131072);
  hipFuncSetAttribute((const void*)gemm_nt<2048, 7168, false>,
                      hipFuncAttributeMaxDynamicSharedMemorySize, 131072);

  // 1) cast inputs to bf16 (single merged launch; wug 64-row gate/up permute)
  cvt_all<<<2048, 256, 0, stream>>>(x, wug, wd, xb, wub, wdb);

  // 2) h = swiglu(x @ w_up_gate^T) fused   [4096, 2048] bf16  (16x16 = 256 blocks)
  gemm_nt<7168, 4096, true><<<256, 512, 131072, stream>>>(xb, wub, h);

  // 3) out = h @ w_down^T     [4096, 7168] fp32  (16x28 = 448 blocks)
  gemm_nt<2048, 7168, false><<<448, 512, 131072, stream>>>(h, wdb, out);
}

// Round 14
// 375.871 us; speedup vs baseline: 1.1049x; 1.1049x over previous
//
#include <hip/hip_runtime.h>
#include <hip/hip_bf16.h>
#include <stdint.h>

// ---------- types ----------
typedef __attribute__((ext_vector_type(8))) short     bf16x8;  // MFMA A/B frag (4 VGPR)
typedef __attribute__((ext_vector_type(4))) float     f32x4;   // MFMA C/D frag

__device__ __forceinline__ unsigned short f2bf(float f) {
  unsigned int u = __float_as_uint(f);
  u += 0x7FFFu + ((u >> 16) & 1u);   // round-to-nearest-even
  return (unsigned short)(u >> 16);
}

__device__ __forceinline__ void async_cp16(const void* g, void* l) {
  __builtin_amdgcn_global_load_lds((const __attribute__((address_space(1))) void*)g,
                                   (__attribute__((address_space(3))) void*)l,
                                   16, 0, 0);
}

// ---------- merged fp32 -> bf16 conversion (one launch for x, wug-perm, wd) --
// float4-unit ranges: x [0, 7340032), wug [7340032, 14680064), wd [.., 18350080)
// wug permute: out row r: g = r>>5, w = r&31; src = g*16 + (w&15) + (w&16?2048:0)
// -> each 32-row group = 16 gate rows + 16 up rows of the same e-block.
__global__ __launch_bounds__(256) void cvt_all(const float* __restrict__ x,
                                               const float* __restrict__ wug,
                                               const float* __restrict__ wd,
                                               unsigned short* __restrict__ xb,
                                               unsigned short* __restrict__ wub,
                                               unsigned short* __restrict__ wdb) {
  int i = blockIdx.x * blockDim.x + threadIdx.x;
  const int stride = gridDim.x * blockDim.x;
  for (; i < 18350080; i += stride) {
    float4 v; ushort4* dp;
    if (i < 7340032) {
      v = ((const float4*)x)[i];
      dp = (ushort4*)xb + i;
    } else if (i < 14680064) {
      const int k = i - 7340032;
      const int r = k / 1792, c = k - r * 1792;
      const int g = r >> 5, w = r & 31;
      const int src = g * 16 + (w & 15) + ((w & 16) ? 2048 : 0);
      v = ((const float4*)wug)[(size_t)src * 1792 + c];
      dp = (ushort4*)wub + k;
    } else {
      const int k = i - 14680064;
      v = ((const float4*)wd)[k];
      dp = (ushort4*)wdb + k;
    }
    ushort4 o;
    o.x = f2bf(v.x); o.y = f2bf(v.y); o.z = f2bf(v.z); o.w = f2bf(v.w);
    *dp = o;
  }
}

// ---------- 256x256 NT bf16 GEMM: BK=64 dbuf, quadrant schedule -------------
// (round-9, the session's verified best: GEMM1 206.8us, 1163 TF, MfmaUtil
//  53.5%, SQ_LDS_BANK_CONFLICT = 0, VGPR 108, no spill)
// C[m,n] = sum_k A[m,k]*B[n,k].  512 thr = 8 waves (2Mx4N), wave-tile 128x64.
// LDS: 2 buffers x (A 32K | B 32K) = 128 KiB. Per K-tile (BK=64), per wave:
//   top  (G_first resident): read A-quad(2wr) 8 + B-quad(wc) 8; stage
//         G_first(t+1)=6; MFMA Q00,Q01 (32); vmcnt(6) [drains G_late(t),
//         ~1 tile old]; barrier
//   bot  (G_late resident):  read A-quad(2wr+1) 8; stage G_late(t+1)=2;
//         MFMA Q11,Q10 (32); vmcnt(2) [drains G_first(t+1)]; barrier
// Residency groups match consumption exactly: G_first = {A q0,q2 (both wr's
// top-half rows), B all}; G_late = {A q1,q3}. Counted vmcnt only, never 0
// (except final tile). No inline lgkm asm — the compiler emits fine-grained
// lgkmcnt for ds_read->MFMA (m97), preserving in-wave read/MFMA overlap.
// Q10 is a pure-register MFMA cluster (B frags live across the tile).
// Swizzle (0-conflict, HW-verified round-9): row r = 128B line; 16B phys slot
// p holds logical q = p ^ (r&7); staging pre-swizzles the per-lane GLOBAL
// source, LDS dest stays linear (m173).
// FUSE_SWIGLU: B rows pre-permuted so acc n in {0,2}=gate, {1,3}=up of the
// same e-cols -> h = silu(g)*u in-lane, write [M, N/2] bf16.
template <int K, int N, bool FUSE_SWIGLU>
__global__ __launch_bounds__(512, 1) void gemm_nt(const unsigned short* __restrict__ A,
                                                  const unsigned short* __restrict__ B,
                                                  void* __restrict__ Cv) {
  extern __shared__ char sm[];   // 131072 B: buf{0,1} x [A 32K | B 32K]
  constexpr int nbx = N / 256;
  constexpr int nwg = (4096 / 256) * nbx;
  constexpr size_t K2 = (size_t)K * 2;
  constexpr int nt = K / 64;     // K-tiles

  // T1: bijective XCD swizzle (nwg % 8 == 0 for both GEMMs)
  const int bid = blockIdx.x;
  constexpr int q8 = nwg / 8;
  const int swz = (bid & 7) * q8 + (bid >> 3);
  const int bx = swz % nbx, by = swz / nbx;
  const int row0 = by * 256, col0 = bx * 256;

  const int tid = threadIdx.x, wave = tid >> 6, lane = tid & 63;
  const int wr = wave >> 2, wc = wave & 3;       // wave 2x4 grid
  const int fr = lane & 15, fg = lane >> 4;      // fragment row / k-group

  // ---- staging setup: per thread 1 load per 8KB quarter (64 rows x 128B) ----
  const int l3 = lane >> 3, p7 = lane & 7;
  const int qgl = p7 ^ l3;                  // pre-swizzled logical 16B slot
  const char* srcA = (const char*)A + (size_t)(row0 + wave * 8 + l3) * K2 + qgl * 16;
  const char* srcB = (const char*)B + (size_t)(col0 + wave * 8 + l3) * K2 + qgl * 16;
  const int dstq = wave * 1024 + lane * 16; // linear dest within a quarter

#define STAGE_AQ(qa, tt, bufo) \
  async_cp16(srcA + (size_t)(qa) * 64 * K2 + (size_t)(tt) * 128, \
             sm + (bufo) + (qa) * 8192 + dstq)
#define STAGE_BQ(qb, tt, bufo) \
  async_cp16(srcB + (size_t)(qb) * 64 * K2 + (size_t)(tt) * 128, \
             sm + (bufo) + 32768 + (qb) * 8192 + dstq)

  // ---- fragment read offsets (swizzled): row r byte = r*128 + ((kk*4+fg)^(r&7))*16
  const int s0 = ((fg) ^ (fr & 7)) << 4;
  const int s1 = ((4 + fg) ^ (fr & 7)) << 4;
  const int offAb = wr * 16384 + fr * 128;        // + mt*2048 + s[kk]
  const int offBb = 32768 + wc * 8192 + fr * 128; // + nt*2048 + s[kk]

  f32x4 acc[8][4];
#pragma unroll
  for (int m = 0; m < 8; ++m)
#pragma unroll
    for (int n = 0; n < 4; ++n) acc[m][n] = (f32x4){0.f, 0.f, 0.f, 0.f};

  // prologue: stage tile 0 (G_first 6, then G_late 2); drain G_first; sync
  STAGE_AQ(0, 0, 0); STAGE_AQ(2, 0, 0);
  STAGE_BQ(0, 0, 0); STAGE_BQ(1, 0, 0); STAGE_BQ(2, 0, 0); STAGE_BQ(3, 0, 0);
  STAGE_AQ(1, 0, 0); STAGE_AQ(3, 0, 0);
  asm volatile("s_waitcnt vmcnt(2)" ::: "memory");
  __builtin_amdgcn_s_barrier();

  // invariant at tile-t top: G_first(t) resident; own outstanding = G_late(t)=2
  for (int t = 0; t < nt; ++t) {
    const char* cur = sm + (t & 1) * 65536;
    const int nxo = ((t + 1) & 1) * 65536;
    const bool more = (t + 1 < nt);

    // ======== first half: Q00 (m0-3 x n0-1), Q01 (m0-3 x n2-3) ========
    bf16x8 a0[4][2], b0[2][2], b1[2][2];
#pragma unroll
    for (int mt = 0; mt < 4; ++mt) {
      a0[mt][0] = *(const bf16x8*)(cur + offAb + mt * 2048 + s0);
      a0[mt][1] = *(const bf16x8*)(cur + offAb + mt * 2048 + s1);
    }
#pragma unroll
    for (int n = 0; n < 2; ++n) {
      b0[n][0] = *(const bf16x8*)(cur + offBb + n * 2048 + s0);
      b0[n][1] = *(const bf16x8*)(cur + offBb + n * 2048 + s1);
      b1[n][0] = *(const bf16x8*)(cur + offBb + (n + 2) * 2048 + s0);
      b1[n][1] = *(const bf16x8*)(cur + offBb + (n + 2) * 2048 + s1);
    }
    if (more) {   // stage G_first(t+1): A quads 0,2 + all B (6 loads)
      STAGE_AQ(0, t + 1, nxo); STAGE_AQ(2, t + 1, nxo);
      STAGE_BQ(0, t + 1, nxo); STAGE_BQ(1, t + 1, nxo);
      STAGE_BQ(2, t + 1, nxo); STAGE_BQ(3, t + 1, nxo);
    }
    __builtin_amdgcn_s_setprio(1);
#pragma unroll
    for (int kk = 0; kk < 2; ++kk)
#pragma unroll
      for (int mt = 0; mt < 4; ++mt) {
#pragma unroll
        for (int n = 0; n < 2; ++n)
          acc[mt][n] = __builtin_amdgcn_mfma_f32_16x16x32_bf16(a0[mt][kk], b0[n][kk], acc[mt][n], 0, 0, 0);
#pragma unroll
        for (int n = 0; n < 2; ++n)
          acc[mt][n + 2] = __builtin_amdgcn_mfma_f32_16x16x32_bf16(a0[mt][kk], b1[n][kk], acc[mt][n + 2], 0, 0, 0);
      }
    __builtin_amdgcn_s_setprio(0);
    if (more) { asm volatile("s_waitcnt vmcnt(6)" ::: "memory"); }  // G_late(t) resident
    else      { asm volatile("s_waitcnt vmcnt(0)" ::: "memory"); }
    __builtin_amdgcn_s_barrier();

    // ======== second half: Q11 (m4-7 x n2-3), Q10 (m4-7 x n0-1) ========
    bf16x8 a1[4][2];
#pragma unroll
    for (int mt = 0; mt < 4; ++mt) {
      a1[mt][0] = *(const bf16x8*)(cur + offAb + (mt + 4) * 2048 + s0);
      a1[mt][1] = *(const bf16x8*)(cur + offAb + (mt + 4) * 2048 + s1);
    }
    if (more) { STAGE_AQ(1, t + 1, nxo); STAGE_AQ(3, t + 1, nxo); }  // G_late(t+1)
    __builtin_amdgcn_s_setprio(1);
#pragma unroll
    for (int kk = 0; kk < 2; ++kk)
#pragma unroll
      for (int mt = 0; mt < 4; ++mt) {
#pragma unroll
        for (int n = 0; n < 2; ++n)
          acc[mt + 4][n + 2] = __builtin_amdgcn_mfma_f32_16x16x32_bf16(a1[mt][kk], b1[n][kk], acc[mt + 4][n + 2], 0, 0, 0);
#pragma unroll
        for (int n = 0; n < 2; ++n)
          acc[mt + 4][n] = __builtin_amdgcn_mfma_f32_16x16x32_bf16(a1[mt][kk], b0[n][kk], acc[mt + 4][n], 0, 0, 0);
      }
    __builtin_amdgcn_s_setprio(0);
    if (more) {
      asm volatile("s_waitcnt vmcnt(2)" ::: "memory");  // G_first(t+1) resident
      __builtin_amdgcn_s_barrier();
    }
  }
#undef STAGE_AQ
#undef STAGE_BQ

  // ---- epilogue: C/D layout col = lane&15, row = (lane>>4)*4 + j (m89-verified) ----
  const int rowb = row0 + wr * 128 + fg * 4;
  if (FUSE_SWIGLU) {
    // acc n in {0,2}: gate; {1,3}: up, same e-cols (pre-permuted B)
    unsigned short* Hp = (unsigned short*)Cv;
    const int ecb = ((col0 + wc * 64) >> 1) + fr;
#pragma unroll
    for (int m = 0; m < 8; ++m)
#pragma unroll
      for (int p = 0; p < 2; ++p)
#pragma unroll
        for (int j = 0; j < 4; ++j) {
          const float gv = acc[m][2 * p][j];
          const float uv = acc[m][2 * p + 1][j];
          const float s  = gv / (1.0f + __expf(-gv));
          Hp[(size_t)(rowb + m * 16 + j) * (N / 2) + (ecb + p * 16)] = f2bf(s * uv);
        }
  } else {
    float* Cp = (float*)Cv;
    const int colb = col0 + wc * 64 + fr;
#pragma unroll
    for (int m = 0; m < 8; ++m)
#pragma unroll
      for (int n = 0; n < 4; ++n)
#pragma unroll
        for (int j = 0; j < 4; ++j)
          Cp[(size_t)(rowb + m * 16 + j) * N + (colb + n * 16)] = acc[m][n][j];
  }
}

// ---------- launch ----------
extern "C" void kernel_launch(void* const* d_in, const int* in_sizes, int n_in,
                              void* d_out, int out_size, void* d_ws, size_t ws_size,
                              hipStream_t stream) {
  const int M = 4096, K = 7168, E = 2048;

  const float* x   = (const float*)d_in[0];  // [M,K]
  const float* wug = (const float*)d_in[1];  // [2E,K]
  const float* wd  = (const float*)d_in[2];  // [K,E]
  float* out = (float*)d_out;                // [M,K]

  // workspace layout (bytes)
  char* ws = (char*)d_ws;
  unsigned short* xb  = (unsigned short*)(ws);               //  58,720,256
  unsigned short* wub = (unsigned short*)(ws + 58720256);    //  58,720,256 (permuted)
  unsigned short* wdb = (unsigned short*)(ws + 117440512);   //  29,360,128
  unsigned short* h   = (unsigned short*)(ws + 146800640);   //  16,777,216
  if (ws_size < 163577856) return;                           // need ~156 MiB

  // allow 128 KiB dynamic LDS (host-side calls, safe under graph capture)
  hipFuncSetAttribute((const void*)gemm_nt<7168, 4096, true>,
                      hipFuncAttributeMaxDynamicSharedMemorySize, 131072);
  hipFuncSetAttribute((const void*)gemm_nt<2048, 7168, false>,
                      hipFuncAttributeMaxDynamicSharedMemorySize, 131072);

  // 1) cast inputs to bf16 (single merged launch; wug with gate/up permutation)
  cvt_all<<<2048, 256, 0, stream>>>(x, wug, wd, xb, wub, wdb);

  // 2) h = swiglu(x @ w_up_gate^T) fused   [4096, 2048] bf16  (16x16 = 256 blocks)
  gemm_nt<7168, 4096, true><<<256, 512, 131072, stream>>>(xb, wub, h);

  // 3) out = h @ w_down^T     [4096, 7168] fp32  (16x28 = 448 blocks)
  gemm_nt<2048, 7168, false><<<448, 512, 131072, stream>>>(h, wdb, out);
}

// Round 15
// 372.006 us; speedup vs baseline: 1.1164x; 1.0104x over previous
//
#include <hip/hip_runtime.h>
#include <hip/hip_bf16.h>
#include <stdint.h>

// ---------- types ----------
typedef __attribute__((ext_vector_type(8))) short     bf16x8;  // MFMA A/B frag (4 VGPR)
typedef __attribute__((ext_vector_type(4))) float     f32x4;   // MFMA C/D frag

__device__ __forceinline__ unsigned short f2bf(float f) {
  unsigned int u = __float_as_uint(f);
  u += 0x7FFFu + ((u >> 16) & 1u);   // round-to-nearest-even
  return (unsigned short)(u >> 16);
}

__device__ __forceinline__ void async_cp16(const void* g, void* l) {
  __builtin_amdgcn_global_load_lds((const __attribute__((address_space(1))) void*)g,
                                   (__attribute__((address_space(3))) void*)l,
                                   16, 0, 0);
}

// ---------- merged fp32 -> bf16 conversion (one launch for x, wug-perm, wd) --
// float4-unit ranges: x [0, 7340032), wug [7340032, 14680064), wd [.., 18350080)
// wug permute: out row r: g = r>>5, w = r&31; src = g*16 + (w&15) + (w&16?2048:0)
// -> each 32-row group = 16 gate rows + 16 up rows of the same e-block.
__global__ __launch_bounds__(256) void cvt_all(const float* __restrict__ x,
                                               const float* __restrict__ wug,
                                               const float* __restrict__ wd,
                                               unsigned short* __restrict__ xb,
                                               unsigned short* __restrict__ wub,
                                               unsigned short* __restrict__ wdb) {
  int i = blockIdx.x * blockDim.x + threadIdx.x;
  const int stride = gridDim.x * blockDim.x;
  for (; i < 18350080; i += stride) {
    float4 v; ushort4* dp;
    if (i < 7340032) {
      v = ((const float4*)x)[i];
      dp = (ushort4*)xb + i;
    } else if (i < 14680064) {
      const int k = i - 7340032;
      const int r = k / 1792, c = k - r * 1792;
      const int g = r >> 5, w = r & 31;
      const int src = g * 16 + (w & 15) + ((w & 16) ? 2048 : 0);
      v = ((const float4*)wug)[(size_t)src * 1792 + c];
      dp = (ushort4*)wub + k;
    } else {
      const int k = i - 14680064;
      v = ((const float4*)wd)[k];
      dp = (ushort4*)wdb + k;
    }
    ushort4 o;
    o.x = f2bf(v.x); o.y = f2bf(v.y); o.z = f2bf(v.z); o.w = f2bf(v.w);
    *dp = o;
  }
}

// ---------- 256x256 NT bf16 GEMM: BK=64 dbuf, 4-PHASE quadrant schedule ----
// Round-9 skeleton (verified best: 1163 TF, 0 conflicts) with the K-tile split
// into 4 barrier-bounded phases (the untested grid cell: 4-phase + counted
// vmcnt + NO inline lgkm / NO sched_barrier — r5 drained vmcnt(0)/tile, r7
// carried the m141 sched_barrier(0) poison; both confounds removed here).
// Per K-tile (BK=64), per wave (quadrant order Q00,Q01,Q11,Q10):
//   PhA: read a0 (8 b128) + b0 (4); stage A0,A2(t+1)=2; 16 MFMA; barrier
//   PhB: read b1 (4);  stage B0..B3(t+1)=4; 16 MFMA; vmcnt(6); barrier
//        [outstanding 8 = G_late(t) oldest 2 + 6 of t+1 -> drains G_late(t)]
//   PhC: read a1 (8);  stage A1,A3(t+1)=2; 16 MFMA; barrier
//   PhD: 16 MFMA (pure register: a1 x b0); vmcnt(2); barrier
//        [drains the 6 G_first(t+1) loads -> resident for t+1 PhA reads]
// Mechanism (m201/T3): each cluster's MFMA issue overlaps the NEXT phase's
// ds_reads via bounded 2-wave/SIMD slip; barriers keep slip at one phase.
// Counted vmcnt only, never 0 except the final tile. The compiler emits
// fine-grained lgkmcnt for ds_read->MFMA (m97) — no hand waits.
// Swizzle (0-conflict, HW-verified): row r = 128B line; 16B phys slot p holds
// logical q = p ^ (r&7); staging pre-swizzles the per-lane GLOBAL source, LDS
// dest stays linear (m173).
// FUSE_SWIGLU: B rows pre-permuted so acc n in {0,2}=gate, {1,3}=up of the
// same e-cols -> h = silu(g)*u in-lane, write [M, N/2] bf16.
template <int K, int N, bool FUSE_SWIGLU>
__global__ __launch_bounds__(512, 1) void gemm_nt(const unsigned short* __restrict__ A,
                                                  const unsigned short* __restrict__ B,
                                                  void* __restrict__ Cv) {
  extern __shared__ char sm[];   // 131072 B: buf{0,1} x [A 32K | B 32K]
  constexpr int nbx = N / 256;
  constexpr int nwg = (4096 / 256) * nbx;
  constexpr size_t K2 = (size_t)K * 2;
  constexpr int nt = K / 64;     // K-tiles

  // T1: bijective XCD swizzle (nwg % 8 == 0 for both GEMMs)
  const int bid = blockIdx.x;
  constexpr int q8 = nwg / 8;
  const int swz = (bid & 7) * q8 + (bid >> 3);
  const int bx = swz % nbx, by = swz / nbx;
  const int row0 = by * 256, col0 = bx * 256;

  const int tid = threadIdx.x, wave = tid >> 6, lane = tid & 63;
  const int wr = wave >> 2, wc = wave & 3;       // wave 2x4 grid
  const int fr = lane & 15, fg = lane >> 4;      // fragment row / k-group

  // ---- staging setup: per thread 1 load per 8KB quarter (64 rows x 128B) ----
  const int l3 = lane >> 3, p7 = lane & 7;
  const int qgl = p7 ^ l3;                  // pre-swizzled logical 16B slot
  const char* srcA = (const char*)A + (size_t)(row0 + wave * 8 + l3) * K2 + qgl * 16;
  const char* srcB = (const char*)B + (size_t)(col0 + wave * 8 + l3) * K2 + qgl * 16;
  const int dstq = wave * 1024 + lane * 16; // linear dest within a quarter

#define STAGE_AQ(qa, tt, bufo) \
  async_cp16(srcA + (size_t)(qa) * 64 * K2 + (size_t)(tt) * 128, \
             sm + (bufo) + (qa) * 8192 + dstq)
#define STAGE_BQ(qb, tt, bufo) \
  async_cp16(srcB + (size_t)(qb) * 64 * K2 + (size_t)(tt) * 128, \
             sm + (bufo) + 32768 + (qb) * 8192 + dstq)

  // ---- fragment read offsets (swizzled): row r byte = r*128 + ((kk*4+fg)^(r&7))*16
  const int s0 = ((fg) ^ (fr & 7)) << 4;
  const int s1 = ((4 + fg) ^ (fr & 7)) << 4;
  const int offAb = wr * 16384 + fr * 128;        // + mt*2048 + s[kk]
  const int offBb = 32768 + wc * 8192 + fr * 128; // + nt*2048 + s[kk]

  f32x4 acc[8][4];
#pragma unroll
  for (int m = 0; m < 8; ++m)
#pragma unroll
    for (int n = 0; n < 4; ++n) acc[m][n] = (f32x4){0.f, 0.f, 0.f, 0.f};

  // prologue: stage tile 0 (G_first 6, then G_late 2); drain G_first; sync
  STAGE_AQ(0, 0, 0); STAGE_AQ(2, 0, 0);
  STAGE_BQ(0, 0, 0); STAGE_BQ(1, 0, 0); STAGE_BQ(2, 0, 0); STAGE_BQ(3, 0, 0);
  STAGE_AQ(1, 0, 0); STAGE_AQ(3, 0, 0);
  asm volatile("s_waitcnt vmcnt(2)" ::: "memory");
  __builtin_amdgcn_s_barrier();

  // invariant at tile-t top: G_first(t) resident; own outstanding = G_late(t)=2
  for (int t = 0; t < nt; ++t) {
    const char* cur = sm + (t & 1) * 65536;
    const int nxo = ((t + 1) & 1) * 65536;
    const bool more = (t + 1 < nt);

    bf16x8 a0[4][2], b0[2][2], b1[2][2], a1[4][2];

    // ======== phase A: Q00 (m0-3 x n0-1) ========
#pragma unroll
    for (int mt = 0; mt < 4; ++mt) {
      a0[mt][0] = *(const bf16x8*)(cur + offAb + mt * 2048 + s0);
      a0[mt][1] = *(const bf16x8*)(cur + offAb + mt * 2048 + s1);
    }
#pragma unroll
    for (int n = 0; n < 2; ++n) {
      b0[n][0] = *(const bf16x8*)(cur + offBb + n * 2048 + s0);
      b0[n][1] = *(const bf16x8*)(cur + offBb + n * 2048 + s1);
    }
    if (more) { STAGE_AQ(0, t + 1, nxo); STAGE_AQ(2, t + 1, nxo); }
    __builtin_amdgcn_s_setprio(1);
#pragma unroll
    for (int kk = 0; kk < 2; ++kk)
#pragma unroll
      for (int mt = 0; mt < 4; ++mt)
#pragma unroll
        for (int n = 0; n < 2; ++n)
          acc[mt][n] = __builtin_amdgcn_mfma_f32_16x16x32_bf16(a0[mt][kk], b0[n][kk], acc[mt][n], 0, 0, 0);
    __builtin_amdgcn_s_setprio(0);
    __builtin_amdgcn_s_barrier();

    // ======== phase B: Q01 (m0-3 x n2-3) ========
#pragma unroll
    for (int n = 0; n < 2; ++n) {
      b1[n][0] = *(const bf16x8*)(cur + offBb + (n + 2) * 2048 + s0);
      b1[n][1] = *(const bf16x8*)(cur + offBb + (n + 2) * 2048 + s1);
    }
    if (more) {
      STAGE_BQ(0, t + 1, nxo); STAGE_BQ(1, t + 1, nxo);
      STAGE_BQ(2, t + 1, nxo); STAGE_BQ(3, t + 1, nxo);
    }
    __builtin_amdgcn_s_setprio(1);
#pragma unroll
    for (int kk = 0; kk < 2; ++kk)
#pragma unroll
      for (int mt = 0; mt < 4; ++mt)
#pragma unroll
        for (int n = 0; n < 2; ++n)
          acc[mt][n + 2] = __builtin_amdgcn_mfma_f32_16x16x32_bf16(a0[mt][kk], b1[n][kk], acc[mt][n + 2], 0, 0, 0);
    __builtin_amdgcn_s_setprio(0);
    if (more) { asm volatile("s_waitcnt vmcnt(6)" ::: "memory"); }  // G_late(t) resident
    else      { asm volatile("s_waitcnt vmcnt(0)" ::: "memory"); }
    __builtin_amdgcn_s_barrier();

    // ======== phase C: Q11 (m4-7 x n2-3) ========
#pragma unroll
    for (int mt = 0; mt < 4; ++mt) {
      a1[mt][0] = *(const bf16x8*)(cur + offAb + (mt + 4) * 2048 + s0);
      a1[mt][1] = *(const bf16x8*)(cur + offAb + (mt + 4) * 2048 + s1);
    }
    if (more) { STAGE_AQ(1, t + 1, nxo); STAGE_AQ(3, t + 1, nxo); }
    __builtin_amdgcn_s_setprio(1);
#pragma unroll
    for (int kk = 0; kk < 2; ++kk)
#pragma unroll
      for (int mt = 0; mt < 4; ++mt)
#pragma unroll
        for (int n = 0; n < 2; ++n)
          acc[mt + 4][n + 2] = __builtin_amdgcn_mfma_f32_16x16x32_bf16(a1[mt][kk], b1[n][kk], acc[mt + 4][n + 2], 0, 0, 0);
    __builtin_amdgcn_s_setprio(0);
    __builtin_amdgcn_s_barrier();

    // ======== phase D: Q10 (m4-7 x n0-1) — pure register ========
    __builtin_amdgcn_s_setprio(1);
#pragma unroll
    for (int kk = 0; kk < 2; ++kk)
#pragma unroll
      for (int mt = 0; mt < 4; ++mt)
#pragma unroll
        for (int n = 0; n < 2; ++n)
          acc[mt + 4][n] = __builtin_amdgcn_mfma_f32_16x16x32_bf16(a1[mt][kk], b0[n][kk], acc[mt + 4][n], 0, 0, 0);
    __builtin_amdgcn_s_setprio(0);
    if (more) {
      asm volatile("s_waitcnt vmcnt(2)" ::: "memory");  // G_first(t+1) resident
      __builtin_amdgcn_s_barrier();
    }
  }
#undef STAGE_AQ
#undef STAGE_BQ

  // ---- epilogue: C/D layout col = lane&15, row = (lane>>4)*4 + j (m89-verified) ----
  const int rowb = row0 + wr * 128 + fg * 4;
  if (FUSE_SWIGLU) {
    // acc n in {0,2}: gate; {1,3}: up, same e-cols (pre-permuted B)
    unsigned short* Hp = (unsigned short*)Cv;
    const int ecb = ((col0 + wc * 64) >> 1) + fr;
#pragma unroll
    for (int m = 0; m < 8; ++m)
#pragma unroll
      for (int p = 0; p < 2; ++p)
#pragma unroll
        for (int j = 0; j < 4; ++j) {
          const float gv = acc[m][2 * p][j];
          const float uv = acc[m][2 * p + 1][j];
          const float s  = gv / (1.0f + __expf(-gv));
          Hp[(size_t)(rowb + m * 16 + j) * (N / 2) + (ecb + p * 16)] = f2bf(s * uv);
        }
  } else {
    float* Cp = (float*)Cv;
    const int colb = col0 + wc * 64 + fr;
#pragma unroll
    for (int m = 0; m < 8; ++m)
#pragma unroll
      for (int n = 0; n < 4; ++n)
#pragma unroll
        for (int j = 0; j < 4; ++j)
          Cp[(size_t)(rowb + m * 16 + j) * N + (colb + n * 16)] = acc[m][n][j];
  }
}

// ---------- launch ----------
extern "C" void kernel_launch(void* const* d_in, const int* in_sizes, int n_in,
                              void* d_out, int out_size, void* d_ws, size_t ws_size,
                              hipStream_t stream) {
  const int M = 4096, K = 7168, E = 2048;

  const float* x   = (const float*)d_in[0];  // [M,K]
  const float* wug = (const float*)d_in[1];  // [2E,K]
  const float* wd  = (const float*)d_in[2];  // [K,E]
  float* out = (float*)d_out;                // [M,K]

  // workspace layout (bytes)
  char* ws = (char*)d_ws;
  unsigned short* xb  = (unsigned short*)(ws);               //  58,720,256
  unsigned short* wub = (unsigned short*)(ws + 58720256);    //  58,720,256 (permuted)
  unsigned short* wdb = (unsigned short*)(ws + 117440512);   //  29,360,128
  unsigned short* h   = (unsigned short*)(ws + 146800640);   //  16,777,216
  if (ws_size < 163577856) return;                           // need ~156 MiB

  // allow 128 KiB dynamic LDS (host-side calls, safe under graph capture)
  hipFuncSetAttribute((const void*)gemm_nt<7168, 4096, true>,
                      hipFuncAttributeMaxDynamicSharedMemorySize, 131072);
  hipFuncSetAttribute((const void*)gemm_nt<2048, 7168, false>,
                      hipFuncAttributeMaxDynamicSharedMemorySize, 131072);

  // 1) cast inputs to bf16 (single merged launch; wug with gate/up permutation)
  cvt_all<<<2048, 256, 0, stream>>>(x, wug, wd, xb, wub, wdb);

  // 2) h = swiglu(x @ w_up_gate^T) fused   [4096, 2048] bf16  (16x16 = 256 blocks)
  gemm_nt<7168, 4096, true><<<256, 512, 131072, stream>>>(xb, wub, h);

  // 3) out = h @ w_down^T     [4096, 7168] fp32  (16x28 = 448 blocks)
  gemm_nt<2048, 7168, false><<<448, 512, 131072, stream>>>(h, wdb, out);
}